// Round 4
// baseline (807.120 us; speedup 1.0000x reference)
//
#include <hip/hip_runtime.h>
#include <hip/hip_bf16.h>

typedef _Float16 half8 __attribute__((ext_vector_type(8)));
typedef _Float16 half4 __attribute__((ext_vector_type(4)));
typedef float floatx4 __attribute__((ext_vector_type(4)));

#define NEDGE 200000
#define BM 128
#define NBLK 1563            /* ceil(200000/128) */
#define NTILES (2 * NBLK)    /* 3126 */
#define NBLOCKS 256

__device__ _Float16 g_w1[256 * 256]; // [n][k] fp16 (transposed W1)
__device__ _Float16 g_w2[256 * 256]; // [n][k] fp16 (transposed W2)

__global__ void prep_weights(const float* __restrict__ W1, const float* __restrict__ W2) {
    int t = blockIdx.x * 256 + threadIdx.x;   // t = k*256 + n
    int k = t >> 8, n = t & 255;
    g_w1[n * 256 + k] = (_Float16)W1[t];
    g_w2[n * 256 + k] = (_Float16)W2[t];
}

// Raw barrier: LDS handoff needs lgkmcnt(0); deliberately NO vmcnt drain so
// prefetched global loads stay in flight across the barrier (m201 pattern).
__device__ __forceinline__ void bar_lds() {
    __builtin_amdgcn_sched_barrier(0);
    asm volatile("s_waitcnt lgkmcnt(0)" ::: "memory");
    __builtin_amdgcn_s_barrier();
    __builtin_amdgcn_sched_barrier(0);
}

__global__ __launch_bounds__(512, 2) void fused_decoder(
    const float* __restrict__ x,
    const int* __restrict__ psrc, const int* __restrict__ pdst,
    const int* __restrict__ nsrc, const int* __restrict__ ndst,
    const float* __restrict__ b1, const float* __restrict__ b2,
    const float* __restrict__ W3, const float* __restrict__ b3,
    float* __restrict__ out)
{
    __shared__ _Float16 eT[2][BM * 256];  // 2 x 64KB, XOR-swizzled rows
    __shared__ float part[BM * 4];        // layer-3 cross-wave partials

    const int tid  = threadIdx.x;
    const int lane = tid & 63;
    const int wid  = tid >> 6;            // 0..7
    const int l15  = lane & 15;
    const int lhi  = lane >> 4;           // 0..3
    const int n0   = (wid & 3) * 64;      // col slice (4 groups of 64)
    const int rowbase = (wid >> 2) * 64;  // row half (2 groups of 64)
    const int grow = wid * 16;            // gather rows owned by this wave

    // loop-invariant per-lane params
    float b1v[4], b2v[4], w3v[4];
    #pragma unroll
    for (int ni = 0; ni < 4; ++ni) {
        b1v[ni] = b1[n0 + ni * 16 + l15];
        b2v[ni] = b2[n0 + ni * 16 + l15];
        w3v[ni] = W3[n0 + ni * 16 + l15];
    }
    const float b3v = b3[0];
    const unsigned aswz  = (unsigned)((l15 & 7) << 4);
    const unsigned abase = (unsigned)((rowbase + l15) * 512 + lhi * 16);

    floatx4 ga[8], gb[8];  // in-flight gather chunk (8 rows)

    auto issue = [&](int c0, const int* sI, const int* dI, int tbase, int trows) {
        #pragma unroll
        for (int t = 0; t < 8; ++t) {
            int row = grow + c0 + t;
            if (row < trows) {
                long s = sI[tbase + row];
                long d = dI[tbase + row];
                ga[t] = *(const floatx4*)(x + s * 256 + lane * 4);
                gb[t] = *(const floatx4*)(x + d * 256 + lane * 4);
            }
        }
    };
    auto consume = [&](_Float16* buf, int c0, int trows) {
        #pragma unroll
        for (int t = 0; t < 8; ++t) {
            int row = grow + c0 + t;
            unsigned addr = ((unsigned)(row * 512 + lane * 8)) ^ ((unsigned)((row & 7) << 4));
            half4 h;
            if (row < trows) {
                h[0] = (_Float16)(ga[t][0] * gb[t][0]);
                h[1] = (_Float16)(ga[t][1] * gb[t][1]);
                h[2] = (_Float16)(ga[t][2] * gb[t][2]);
                h[3] = (_Float16)(ga[t][3] * gb[t][3]);
            } else {
                h = (half4){0, 0, 0, 0};
            }
            *(half4*)((char*)buf + addr) = h;
        }
    };

    floatx4 acc[4][4];
    auto mm = [&](const _Float16* buf, const _Float16* gw) {
        #pragma unroll
        for (int mi = 0; mi < 4; ++mi)
            #pragma unroll
            for (int ni = 0; ni < 4; ++ni)
                acc[mi][ni] = (floatx4){0.f, 0.f, 0.f, 0.f};
        const _Float16* __restrict__ wb = gw + (n0 + l15) * 256 + lhi * 8;
        half8 bcur[4], bnext[4];
        #pragma unroll
        for (int ni = 0; ni < 4; ++ni) bcur[ni] = *(const half8*)(wb + ni * 4096);
        #pragma unroll
        for (int kk = 0; kk < 8; ++kk) {
            if (kk < 7) {
                #pragma unroll
                for (int ni = 0; ni < 4; ++ni)
                    bnext[ni] = *(const half8*)(wb + ni * 4096 + (kk + 1) * 32);
            }
            #pragma unroll
            for (int mi = 0; mi < 4; ++mi) {
                half8 a = *(const half8*)((char*)buf + ((abase + mi * 8192 + kk * 64) ^ aswz));
                #pragma unroll
                for (int ni = 0; ni < 4; ++ni)
                    acc[mi][ni] = __builtin_amdgcn_mfma_f32_16x16x32_f16(a, bcur[ni], acc[mi][ni], 0, 0, 0);
            }
            #pragma unroll
            for (int ni = 0; ni < 4; ++ni) bcur[ni] = bnext[ni];
        }
    };

    // ---- tile 0 params + prologue gather ----
    const int t0 = blockIdx.x;
    const int *sI, *dI; int base, obase, rows;
    {
        bool pos = t0 < NBLK; int tb = pos ? t0 : t0 - NBLK;
        sI = pos ? psrc : nsrc; dI = pos ? pdst : ndst;
        base = tb * BM; obase = pos ? 0 : NEDGE; rows = min(BM, NEDGE - base);
    }
    issue(0, sI, dI, base, rows);
    consume(eT[0], 0, rows);
    issue(8, sI, dI, base, rows);
    consume(eT[0], 8, rows);
    bar_lds();

    int cur = 0;
    for (int t = t0; t < NTILES; t += NBLOCKS) {
        const int tn = t + NBLOCKS;
        const bool hasNext = tn < NTILES;
        const int *sIn = sI, *dIn = dI; int basen = base, obasen = obase, rowsn = rows;
        if (hasNext) {
            bool pos = tn < NBLK; int tb = pos ? tn : tn - NBLK;
            sIn = pos ? psrc : nsrc; dIn = pos ? pdst : ndst;
            basen = tb * BM; obasen = pos ? 0 : NEDGE; rowsn = min(BM, NEDGE - basen);
        }
        _Float16* bc = eT[cur];
        _Float16* bn = eT[cur ^ 1];

        // ---- phase 1: issue prefetch chunk A (tile t+1) + layer 1 ----
        if (hasNext) issue(0, sIn, dIn, basen, rowsn);
        mm(bc, g_w1);
        bar_lds();

        // ---- phase 2: h1 bias+relu writeback + consume chunk A ----
        #pragma unroll
        for (int mi = 0; mi < 4; ++mi)
            #pragma unroll
            for (int ni = 0; ni < 4; ++ni)
                #pragma unroll
                for (int r = 0; r < 4; ++r) {
                    float h = fmaxf(acc[mi][ni][r] + b1v[ni], 0.f);
                    int row = rowbase + mi * 16 + lhi * 4 + r;
                    int col = n0 + ni * 16 + l15;
                    unsigned addr = ((unsigned)(row * 512 + col * 2)) ^ ((unsigned)((row & 7) << 4));
                    *(_Float16*)((char*)bc + addr) = (_Float16)h;
                }
        if (hasNext) consume(bn, 0, rowsn);
        bar_lds();

        // ---- phase 3: issue prefetch chunk B + layer 2 + layer 3 partials ----
        if (hasNext) issue(8, sIn, dIn, basen, rowsn);
        mm(bc, g_w2);
        #pragma unroll
        for (int mi = 0; mi < 4; ++mi)
            #pragma unroll
            for (int r = 0; r < 4; ++r) {
                float s = 0.f;
                #pragma unroll
                for (int ni = 0; ni < 4; ++ni)
                    s += fmaxf(acc[mi][ni][r] + b2v[ni], 0.f) * w3v[ni];
                s += __shfl_xor(s, 1);
                s += __shfl_xor(s, 2);
                s += __shfl_xor(s, 4);
                s += __shfl_xor(s, 8);
                if (l15 == 0) {
                    int row = rowbase + mi * 16 + lhi * 4 + r;
                    part[row * 4 + (wid & 3)] = s;
                }
            }
        bar_lds();

        // ---- phase 4: output store + consume chunk B ----
        if (tid < BM && tid < rows) {
            floatx4 p = *(const floatx4*)(part + tid * 4);
            out[obase + base + tid] = p[0] + p[1] + p[2] + p[3] + b3v;
        }
        if (hasNext) consume(bn, 8, rowsn);
        bar_lds();

        cur ^= 1;
        sI = sIn; dI = dIn; base = basen; obase = obasen; rows = rowsn;
    }
}

extern "C" void kernel_launch(void* const* d_in, const int* in_sizes, int n_in,
                              void* d_out, int out_size, void* d_ws, size_t ws_size,
                              hipStream_t stream) {
    const float* x    = (const float*)d_in[0];
    const int* psrc   = (const int*)d_in[1];
    const int* pdst   = (const int*)d_in[2];
    const int* nsrc   = (const int*)d_in[3];
    const int* ndst   = (const int*)d_in[4];
    const float* W1   = (const float*)d_in[5];
    const float* b1   = (const float*)d_in[6];
    const float* W2   = (const float*)d_in[7];
    const float* b2   = (const float*)d_in[8];
    const float* W3   = (const float*)d_in[9];
    const float* b3   = (const float*)d_in[10];

    prep_weights<<<256, 256, 0, stream>>>(W1, W2);
    fused_decoder<<<NBLOCKS, 512, 0, stream>>>(x, psrc, pdst, nsrc, ndst,
                                               b1, b2, W3, b3, (float*)d_out);
}

// Round 5
// 585.573 us; speedup vs baseline: 1.3783x; 1.3783x over previous
//
#include <hip/hip_runtime.h>
#include <hip/hip_bf16.h>

typedef _Float16 half8 __attribute__((ext_vector_type(8)));
typedef _Float16 half4 __attribute__((ext_vector_type(4)));
typedef float floatx4 __attribute__((ext_vector_type(4)));

#define NEDGE 200000
#define BM 64
#define NPOS 3125            /* 200000/64 */
#define NTILES (2 * NPOS)    /* 6250 */
#define NBLOCKS 256

__device__ _Float16 g_w1[256 * 256];      // [n][k] fp16 (transposed W1)
__device__ _Float16 g_w2[256 * 256];      // [n][k] fp16 (transposed W2)
__device__ _Float16 g_xh[100000L * 256];  // fp16 copy of x (51.2 MB, L3-resident)

__global__ void prep_weights(const float* __restrict__ W1, const float* __restrict__ W2) {
    int t = blockIdx.x * 256 + threadIdx.x;   // t = k*256 + n
    int k = t >> 8, n = t & 255;
    g_w1[n * 256 + k] = (_Float16)W1[t];
    g_w2[n * 256 + k] = (_Float16)W2[t];
}

__global__ void prep_x(const float* __restrict__ x) {
    long i = ((long)blockIdx.x * 256 + threadIdx.x) * 8;  // 12500 blocks exact
    floatx4 v0 = *(const floatx4*)(x + i);
    floatx4 v1 = *(const floatx4*)(x + i + 4);
    half8 h;
    h[0] = (_Float16)v0[0]; h[1] = (_Float16)v0[1];
    h[2] = (_Float16)v0[2]; h[3] = (_Float16)v0[3];
    h[4] = (_Float16)v1[0]; h[5] = (_Float16)v1[1];
    h[6] = (_Float16)v1[2]; h[7] = (_Float16)v1[3];
    *(half8*)(g_xh + i) = h;
}

// async global->LDS, 16B/lane; LDS dest = uniform base + lane*16
#define GLOAD_LDS16(g, l) \
    __builtin_amdgcn_global_load_lds((const __attribute__((address_space(1))) unsigned int*)(g), \
                                     (__attribute__((address_space(3))) unsigned int*)(l), 16, 0, 0)

#define VMCNT(n) asm volatile("s_waitcnt vmcnt(" #n ")" ::: "memory")

// LDS-publish barrier WITHOUT vmcnt drain (prefetch stays in flight)
__device__ __forceinline__ void bar_lds() {
    __builtin_amdgcn_sched_barrier(0);
    asm volatile("s_waitcnt lgkmcnt(0)" ::: "memory");
    __builtin_amdgcn_s_barrier();
    __builtin_amdgcn_sched_barrier(0);
}

__global__ __launch_bounds__(512, 2) void fused_decoder(
    const int* __restrict__ psrc, const int* __restrict__ pdst,
    const int* __restrict__ nsrc, const int* __restrict__ ndst,
    const float* __restrict__ b1, const float* __restrict__ b2,
    const float* __restrict__ W3, const float* __restrict__ b3,
    float* __restrict__ out)
{
    __shared__ _Float16 bufS[2][BM * 256];  // 2 x 32KB, rows XOR-swizzled
    __shared__ _Float16 bufD[2][BM * 256];  // 2 x 32KB
    __shared__ float part[BM * 4];          // 1KB

    const int tid  = threadIdx.x;
    const int lane = tid & 63;
    const int wid  = tid >> 6;        // 0..7
    const int l15  = lane & 15;
    const int lhi  = lane >> 4;       // 0..3
    const int mr   = wid >> 2;        // 0..1: row half [mr*32, +32)
    const int nc   = wid & 3;         // 0..3: col quarter
    const int n0   = nc * 64;
    // gather role: waves 0-3 stage S rows [w*16,+16), waves 4-7 stage D rows
    const int  grow0 = (wid & 3) * 16;
    const bool gIsD  = wid >= 4;

    float b1v[4], b2v[4], w3v[4];
    #pragma unroll
    for (int ni = 0; ni < 4; ++ni) {
        b1v[ni] = b1[n0 + ni * 16 + l15];
        b2v[ni] = b2[n0 + ni * 16 + l15];
        w3v[ni] = W3[n0 + ni * 16 + l15];
    }
    const float b3v = b3[0];
    const unsigned aswz  = (unsigned)((l15 & 7) << 4);
    const unsigned abase = (unsigned)((mr * 32 + l15) * 512 + lhi * 16);

    int ipf[8];  // prefetched row indices (uniform per half-wave)

    auto loadidx = [&](int tt) {
        bool pos = tt < NPOS; int tb = pos ? tt : tt - NPOS;
        const int* __restrict__ I = gIsD ? (pos ? pdst : ndst) : (pos ? psrc : nsrc);
        int ib = tb * BM + grow0 + (lane >> 5);
        #pragma unroll
        for (int i = 0; i < 8; ++i) ipf[i] = I[ib + 2 * i];
    };

    auto issueg = [&](int cb) {
        _Float16* sb = gIsD ? bufD[cb] : bufS[cb];
        #pragma unroll
        for (int i = 0; i < 8; ++i) {
            int r = grow0 + 2 * i + (lane >> 5);
            const char* g = (const char*)g_xh + (long)ipf[i] * 512
                          + (((lane & 31) ^ (r & 7)) * 16);   // pre-swizzled source chunk
            char* l = (char*)sb + (grow0 + 2 * i) * 512;      // uniform; lanes fill 1KB = 2 rows
            GLOAD_LDS16(g, l);
        }
    };

    floatx4 acc[2][4];
    auto mml = [&](const _Float16* __restrict__ gw, int cb, bool prod) {
        #pragma unroll
        for (int mi = 0; mi < 2; ++mi)
            #pragma unroll
            for (int ni = 0; ni < 4; ++ni)
                acc[mi][ni] = (floatx4){0.f, 0.f, 0.f, 0.f};
        const _Float16* __restrict__ wb = gw + (n0 + l15) * 256 + lhi * 8;
        half8 bcur[4], bnext[4];
        #pragma unroll
        for (int ni = 0; ni < 4; ++ni) bcur[ni] = *(const half8*)(wb + ni * 4096);
        #pragma unroll
        for (int kk = 0; kk < 8; ++kk) {
            if (kk < 7) {
                #pragma unroll
                for (int ni = 0; ni < 4; ++ni)
                    bnext[ni] = *(const half8*)(wb + ni * 4096 + (kk + 1) * 32);
            }
            #pragma unroll
            for (int mi = 0; mi < 2; ++mi) {
                unsigned ao = (abase + mi * 8192 + kk * 64) ^ aswz;
                half8 a = *(const half8*)((char*)bufS[cb] + ao);
                if (prod) {
                    half8 ad = *(const half8*)((char*)bufD[cb] + ao);
                    a = a * ad;   // v_pk_mul_f16: e = x[s]*x[d] on the fly
                }
                #pragma unroll
                for (int ni = 0; ni < 4; ++ni)
                    acc[mi][ni] = __builtin_amdgcn_mfma_f32_16x16x32_f16(a, bcur[ni], acc[mi][ni], 0, 0, 0);
            }
            #pragma unroll
            for (int ni = 0; ni < 4; ++ni) bcur[ni] = bnext[ni];
        }
    };

    // ---------------- prologue: gather t0, prefetch idx t1 ----------------
    const int t0 = blockIdx.x;
    int cur = 0;
    loadidx(t0);          // auto vmcnt on use
    issueg(0);
    loadidx(t0 + NBLOCKS);   // always valid (t0+255+256 < 6250)
    VMCNT(8);             // 8 gathers done; 8 idx loads may fly
    bar_lds();

    // ---------------- main loop ----------------
    for (int t = t0; t < NTILES; t += NBLOCKS) {
        const bool hasN1 = (t + NBLOCKS)     < NTILES;
        const bool hasN2 = (t + 2 * NBLOCKS) < NTILES;

        if (hasN1) issueg(cur ^ 1);      // gathers for t+1 (uses ipf = idx(t+1))
        if (hasN2) loadidx(t + 2 * NBLOCKS);

        // layer 1 (A = S*D product from LDS)
        mml(g_w1, cur, true);
        bar_lds();                        // all waves' L1 A-reads done before overwrite

        // h1 bias+relu writeback into bufS[cur]
        #pragma unroll
        for (int mi = 0; mi < 2; ++mi)
            #pragma unroll
            for (int ni = 0; ni < 4; ++ni)
                #pragma unroll
                for (int r = 0; r < 4; ++r) {
                    float h = fmaxf(acc[mi][ni][r] + b1v[ni], 0.f);
                    int row = mr * 32 + mi * 16 + lhi * 4 + r;
                    int col = n0 + ni * 16 + l15;
                    unsigned addr = ((unsigned)(row * 512 + col * 2)) ^ ((unsigned)((row & 7) << 4));
                    *(_Float16*)((char*)bufS[cur] + addr) = (_Float16)h;
                }
        bar_lds();                        // h1 published

        // layer 2 + layer 3 partials
        mml(g_w2, cur, false);
        #pragma unroll
        for (int mi = 0; mi < 2; ++mi)
            #pragma unroll
            for (int r = 0; r < 4; ++r) {
                float s = 0.f;
                #pragma unroll
                for (int ni = 0; ni < 4; ++ni)
                    s += fmaxf(acc[mi][ni][r] + b2v[ni], 0.f) * w3v[ni];
                s += __shfl_xor(s, 1);
                s += __shfl_xor(s, 2);
                s += __shfl_xor(s, 4);
                s += __shfl_xor(s, 8);
                if (l15 == 0) part[(mr * 32 + mi * 16 + lhi * 4 + r) * 4 + nc] = s;
            }

        // gathers(t+1) must be complete before publish; idx(t+2) may stay in flight
        if (hasN2) { VMCNT(8); } else { VMCNT(0); }
        bar_lds();

        // output store for tile t
        {
            bool pos = t < NPOS; int tb = pos ? t : t - NPOS;
            int base = tb * BM; int ob = pos ? 0 : NEDGE;
            if (tid < BM) {
                floatx4 p = *(const floatx4*)(part + tid * 4);
                out[ob + base + tid] = p[0] + p[1] + p[2] + p[3] + b3v;
            }
        }
        cur ^= 1;
    }
}

extern "C" void kernel_launch(void* const* d_in, const int* in_sizes, int n_in,
                              void* d_out, int out_size, void* d_ws, size_t ws_size,
                              hipStream_t stream) {
    const float* x    = (const float*)d_in[0];
    const int* psrc   = (const int*)d_in[1];
    const int* pdst   = (const int*)d_in[2];
    const int* nsrc   = (const int*)d_in[3];
    const int* ndst   = (const int*)d_in[4];
    const float* W1   = (const float*)d_in[5];
    const float* b1   = (const float*)d_in[6];
    const float* W2   = (const float*)d_in[7];
    const float* b2   = (const float*)d_in[8];
    const float* W3   = (const float*)d_in[9];
    const float* b3   = (const float*)d_in[10];

    prep_weights<<<256, 256, 0, stream>>>(W1, W2);
    prep_x<<<12500, 256, 0, stream>>>(x);
    fused_decoder<<<NBLOCKS, 512, 0, stream>>>(psrc, pdst, nsrc, ndst,
                                               b1, b2, W3, b3, (float*)d_out);
}

// Round 6
// 340.575 us; speedup vs baseline: 2.3699x; 1.7194x over previous
//
#include <hip/hip_runtime.h>
#include <hip/hip_bf16.h>

typedef _Float16 half8 __attribute__((ext_vector_type(8)));
typedef float floatx4 __attribute__((ext_vector_type(4)));

#define NEDGE 200000
#define ETOT  400000
#define BM 128
#define NTILES (ETOT / BM)   /* 3125 exact */

__device__ _Float16 g_w1[256 * 256];       // [n][k] fp16 (transposed W1)
__device__ _Float16 g_w2[256 * 256];       // [n][k] fp16 (transposed W2)
__device__ _Float16 g_xh[100000L * 256];   // fp16 x (51.2 MB)
__device__ _Float16 g_e[(long)ETOT * 256]; // fp16 e = x[s]*x[d] (204.8 MB)

__global__ void prep_weights(const float* __restrict__ W1, const float* __restrict__ W2) {
    int t = blockIdx.x * 256 + threadIdx.x;   // t = k*256 + n
    int k = t >> 8, n = t & 255;
    g_w1[n * 256 + k] = (_Float16)W1[t];
    g_w2[n * 256 + k] = (_Float16)W2[t];
}

__global__ void prep_x(const float* __restrict__ x) {
    long i = ((long)blockIdx.x * 256 + threadIdx.x) * 8;  // 12500 blocks exact
    floatx4 v0 = *(const floatx4*)(x + i);
    floatx4 v1 = *(const floatx4*)(x + i + 4);
    half8 h;
    h[0] = (_Float16)v0[0]; h[1] = (_Float16)v0[1];
    h[2] = (_Float16)v0[2]; h[3] = (_Float16)v0[3];
    h[4] = (_Float16)v1[0]; h[5] = (_Float16)v1[1];
    h[6] = (_Float16)v1[2]; h[7] = (_Float16)v1[3];
    *(half8*)(g_xh + i) = h;
}

// ---- K2: pure gather + product, max occupancy, no LDS/barriers ----
// 32 lanes per edge (16B/lane); 8 edges per 256-thread block; 50000 blocks.
__global__ __launch_bounds__(256) void gather_product(
    const int* __restrict__ psrc, const int* __restrict__ pdst,
    const int* __restrict__ nsrc, const int* __restrict__ ndst)
{
    int gid = blockIdx.x * 256 + threadIdx.x;
    int e = gid >> 5;
    int c = (gid & 31) * 8;
    int s, d;
    if (e < NEDGE) { s = psrc[e]; d = pdst[e]; }
    else           { s = nsrc[e - NEDGE]; d = ndst[e - NEDGE]; }
    half8 a = *(const half8*)(g_xh + (long)s * 256 + c);
    half8 b = *(const half8*)(g_xh + (long)d * 256 + c);
    *(half8*)(g_e + (long)e * 256 + c) = a * b;
}

// async global->LDS, 16B/lane
#define GLOAD_LDS16(g, l) \
    __builtin_amdgcn_global_load_lds((const __attribute__((address_space(1))) unsigned int*)(g), \
                                     (__attribute__((address_space(3))) unsigned int*)(l), 16, 0, 0)

// ---- K3: MLP over linear e tiles (r1 MFMA structure) ----
__global__ __launch_bounds__(256, 2) void mlp(
    const float* __restrict__ b1, const float* __restrict__ b2,
    const float* __restrict__ W3, const float* __restrict__ b3,
    float* __restrict__ out)
{
    __shared__ _Float16 eT[BM * 256];   // 64KB, rows XOR-swizzled
    __shared__ float part[BM * 4];

    const int tid  = threadIdx.x;
    const int lane = tid & 63;
    const int wid  = tid >> 6;     // 0..3: col quarter
    const int n0   = wid * 64;
    const int l15  = lane & 15;
    const int lhi  = lane >> 4;

    // stage e-tile: wave w loads rows [w*32, w*32+32), 2 rows per gload_lds.
    // LDS dest is linear; source chunk pre-swizzled by ^(row&7) (rule 21).
    {
        const long ebase = (long)blockIdx.x * BM * 256;
        const int half = lane >> 5;             // 0,1: which of the 2 rows
        const int ch   = lane & 31;             // chunk within row
        #pragma unroll
        for (int j = 0; j < 16; ++j) {
            int r2  = wid * 32 + 2 * j;
            int row = r2 + half;
            const char* g = (const char*)(g_e + ebase + (long)row * 256)
                          + ((ch ^ (row & 7)) * 16);
            GLOAD_LDS16(g, (char*)eT + r2 * 512);
        }
        asm volatile("s_waitcnt vmcnt(0)" ::: "memory");
    }
    __syncthreads();

    const unsigned alin = (unsigned)(l15 * 512 + lhi * 16);
    const unsigned aswz = (unsigned)((l15 & 7) << 4);

    floatx4 acc[8][4];

    // ---------------- layer 1 ----------------
    #pragma unroll
    for (int mi = 0; mi < 8; ++mi)
        #pragma unroll
        for (int ni = 0; ni < 4; ++ni)
            acc[mi][ni] = (floatx4){0.f, 0.f, 0.f, 0.f};
    {
        const _Float16* __restrict__ wb = g_w1 + (n0 + l15) * 256 + lhi * 8;
        half8 bcur[4], bnext[4];
        #pragma unroll
        for (int ni = 0; ni < 4; ++ni) bcur[ni] = *(const half8*)(wb + ni * 4096);
        #pragma unroll
        for (int kk = 0; kk < 8; ++kk) {
            if (kk < 7) {
                #pragma unroll
                for (int ni = 0; ni < 4; ++ni)
                    bnext[ni] = *(const half8*)(wb + ni * 4096 + (kk + 1) * 32);
            }
            #pragma unroll
            for (int mi = 0; mi < 8; ++mi) {
                half8 a = *(const half8*)((char*)eT + ((alin + mi * 8192 + kk * 64) ^ aswz));
                #pragma unroll
                for (int ni = 0; ni < 4; ++ni)
                    acc[mi][ni] = __builtin_amdgcn_mfma_f32_16x16x32_f16(a, bcur[ni], acc[mi][ni], 0, 0, 0);
            }
            #pragma unroll
            for (int ni = 0; ni < 4; ++ni) bcur[ni] = bnext[ni];
        }
    }
    // bias + relu, write h1 back (same swizzle)
    {
        float b1v[4];
        #pragma unroll
        for (int ni = 0; ni < 4; ++ni) b1v[ni] = b1[n0 + ni * 16 + l15];
        __syncthreads();
        #pragma unroll
        for (int mi = 0; mi < 8; ++mi)
            #pragma unroll
            for (int ni = 0; ni < 4; ++ni)
                #pragma unroll
                for (int r = 0; r < 4; ++r) {
                    float h = fmaxf(acc[mi][ni][r] + b1v[ni], 0.f);
                    int row = mi * 16 + lhi * 4 + r;
                    int col = n0 + ni * 16 + l15;
                    unsigned addr = ((unsigned)(row * 512 + col * 2)) ^ ((unsigned)((row & 7) << 4));
                    *(_Float16*)((char*)eT + addr) = (_Float16)h;
                }
        __syncthreads();
    }

    // ---------------- layer 2 ----------------
    #pragma unroll
    for (int mi = 0; mi < 8; ++mi)
        #pragma unroll
        for (int ni = 0; ni < 4; ++ni)
            acc[mi][ni] = (floatx4){0.f, 0.f, 0.f, 0.f};
    {
        const _Float16* __restrict__ wb = g_w2 + (n0 + l15) * 256 + lhi * 8;
        half8 bcur[4], bnext[4];
        #pragma unroll
        for (int ni = 0; ni < 4; ++ni) bcur[ni] = *(const half8*)(wb + ni * 4096);
        #pragma unroll
        for (int kk = 0; kk < 8; ++kk) {
            if (kk < 7) {
                #pragma unroll
                for (int ni = 0; ni < 4; ++ni)
                    bnext[ni] = *(const half8*)(wb + ni * 4096 + (kk + 1) * 32);
            }
            #pragma unroll
            for (int mi = 0; mi < 8; ++mi) {
                half8 a = *(const half8*)((char*)eT + ((alin + mi * 8192 + kk * 64) ^ aswz));
                #pragma unroll
                for (int ni = 0; ni < 4; ++ni)
                    acc[mi][ni] = __builtin_amdgcn_mfma_f32_16x16x32_f16(a, bcur[ni], acc[mi][ni], 0, 0, 0);
            }
            #pragma unroll
            for (int ni = 0; ni < 4; ++ni) bcur[ni] = bnext[ni];
        }
    }

    // ---------------- layer 3 ----------------
    float w3v[4], b2v[4];
    #pragma unroll
    for (int ni = 0; ni < 4; ++ni) {
        b2v[ni] = b2[n0 + ni * 16 + l15];
        w3v[ni] = W3[n0 + ni * 16 + l15];
    }
    __syncthreads();
    #pragma unroll
    for (int mi = 0; mi < 8; ++mi)
        #pragma unroll
        for (int r = 0; r < 4; ++r) {
            float s = 0.f;
            #pragma unroll
            for (int ni = 0; ni < 4; ++ni)
                s += fmaxf(acc[mi][ni][r] + b2v[ni], 0.f) * w3v[ni];
            s += __shfl_xor(s, 1);
            s += __shfl_xor(s, 2);
            s += __shfl_xor(s, 4);
            s += __shfl_xor(s, 8);
            if (l15 == 0) {
                int row = mi * 16 + lhi * 4 + r;
                part[row * 4 + wid] = s;
            }
        }
    __syncthreads();
    if (tid < BM) {
        floatx4 p = *(const floatx4*)(part + tid * 4);
        out[blockIdx.x * BM + tid] = p[0] + p[1] + p[2] + p[3] + b3[0];
    }
}

extern "C" void kernel_launch(void* const* d_in, const int* in_sizes, int n_in,
                              void* d_out, int out_size, void* d_ws, size_t ws_size,
                              hipStream_t stream) {
    const float* x    = (const float*)d_in[0];
    const int* psrc   = (const int*)d_in[1];
    const int* pdst   = (const int*)d_in[2];
    const int* nsrc   = (const int*)d_in[3];
    const int* ndst   = (const int*)d_in[4];
    const float* W1   = (const float*)d_in[5];
    const float* b1   = (const float*)d_in[6];
    const float* W2   = (const float*)d_in[7];
    const float* b2   = (const float*)d_in[8];
    const float* W3   = (const float*)d_in[9];
    const float* b3   = (const float*)d_in[10];

    prep_weights<<<256, 256, 0, stream>>>(W1, W2);
    prep_x<<<12500, 256, 0, stream>>>(x);
    gather_product<<<ETOT / 8, 256, 0, stream>>>(psrc, pdst, nsrc, ndst);
    mlp<<<NTILES, 256, 0, stream>>>(b1, b2, W3, b3, (float*)d_out);
}